// Round 10
// baseline (3400.751 us; speedup 1.0000x reference)
//
#include <hip/hip_runtime.h>
#include <cstdint>
#include <cstddef>

#define A_N 100000
#define B_N 200000
#define M_N 20000
#define POOL_N 220000   // M_N + B_N
#define HD 256
#define MAX_NB 10
#define N_MOLS 2000
#define ATOM_FDIM 35
#define FB_DIM 40

typedef unsigned short u16;
typedef __attribute__((ext_vector_type(8))) short bf16x8;
typedef __attribute__((ext_vector_type(4))) float f32x4;

// Static device buffers (BSS, ~646 MB).
__device__ u16 g_msg0[(size_t)B_N * HD];      // bf16 messages (ping)
__device__ u16 g_msg1[(size_t)B_N * HD];      // bf16 messages (pong)
__device__ u16 g_tmsgh[(size_t)M_N * HD];     // bf16 tree messages
__device__ u16 g_P[(size_t)POOL_N * HD];      // P = pool @ W_h   (bf16)
__device__ u16 g_Q[(size_t)POOL_N * HD];      // Q = pool @ Wo[35:291] (bf16)
__device__ u16 g_binH[(size_t)B_N * HD];      // bf16 binput
__device__ float g_F[(size_t)A_N * HD];       // fp32 fatoms@Wo_top + bias
// packed split-bf16 weights in MFMA A-fragment order: [(c*16+t)*64+lane]*8+j
__device__ u16 g_pWh_hi[65536], g_pWh_lo[65536];
__device__ u16 g_pWo_hi[65536], g_pWo_lo[65536];
__device__ float g_counts[N_MOLS];

__device__ __forceinline__ u16 f2b(float f)
{
    union { float f; unsigned u; } x; x.f = f;
    const unsigned r = x.u + 0x7FFFu + ((x.u >> 16) & 1u);
    return (u16)(r >> 16);
}
__device__ __forceinline__ float b2f(u16 h) { return __uint_as_float((unsigned)h << 16); }
__device__ __forceinline__ float blo(unsigned u) { return __uint_as_float(u << 16); }
__device__ __forceinline__ float bhi(unsigned u) { return __uint_as_float(u & 0xffff0000u); }

// ---------------- setup kernels ----------------
__global__ __launch_bounds__(256)
void k_zero_out(float* __restrict__ p, int n)
{
    const int i = blockIdx.x * 256 + threadIdx.x;
    if (i < n) p[i] = 0.f;
}

__global__ __launch_bounds__(256)
void k_zero_counts()
{
    const int i = blockIdx.x * 256 + threadIdx.x;
    if (i < N_MOLS) g_counts[i] = 0.f;
}

__global__ __launch_bounds__(256)
void k_cvt(const float* __restrict__ tmsg)
{
    const int i = (blockIdx.x * 256 + threadIdx.x) * 4;
    if (i < M_N * HD) {
        const float4 v = *(const float4*)(tmsg + i);
        ushort4 o;
        o.x = f2b(v.x); o.y = f2b(v.y); o.z = f2b(v.z); o.w = f2b(v.w);
        *(ushort4*)(g_tmsgh + i) = o;
    }
}

// pack Wh and Wo[35:291] into split-bf16 MFMA A-fragment layout.
// A[m'=lane&15][k=(lane>>4)*8+j] for n-tile t, k-chunk c:
//   packed[((c*16+t)*64+lane)*8+j] = W[c*32+(lane>>4)*8+j][t*16+(lane&15)]
__global__ __launch_bounds__(256)
void k_packW(const float* __restrict__ Wh, const float* __restrict__ Wo)
{
    const int id = blockIdx.x * 256 + threadIdx.x;   // 0..8191
    if (id >= 8192) return;
    const int l = id & 63;
    const int t = (id >> 6) & 15;
    const int c = id >> 10;
    const int n = t * 16 + (l & 15);
    const int kb = c * 32 + ((l >> 4) << 3);
    const size_t base = (size_t)id * 8;
    #pragma unroll
    for (int j = 0; j < 8; ++j) {
        const int k = kb + j;
        const float wh = Wh[(size_t)k * HD + n];
        const u16 hh = f2b(wh);
        g_pWh_hi[base + j] = hh;
        g_pWh_lo[base + j] = f2b(wh - b2f(hh));
        const float wo = Wo[(size_t)(35 + k) * HD + n];
        const u16 oh = f2b(wo);
        g_pWo_hi[base + j] = oh;
        g_pWo_lo[base + j] = f2b(wo - b2f(oh));
    }
}

// ---------------- K1: binH = bf16(fbonds @ W_i); msg0 = bf16(relu(binput)) ----------------
__global__ __launch_bounds__(256)
void k_in(const float* __restrict__ fbonds, const float* __restrict__ Wi)
{
    __shared__ float Ws[FB_DIM * HD];                      // 40 KB
    for (int i = threadIdx.x; i < FB_DIM * HD; i += 256) Ws[i] = Wi[i];
    __syncthreads();
    const int lane = threadIdx.x & 63;
    const int wid  = (blockIdx.x * 256 + threadIdx.x) >> 6;
    const int nw   = (gridDim.x * 256) >> 6;
    for (int row = wid; row < B_N; row += nw) {
        const float* fr = fbonds + (size_t)row * FB_DIM;
        float ax = 0.f, ay = 0.f, az = 0.f, aw = 0.f;
        #pragma unroll
        for (int q = 0; q < FB_DIM / 4; ++q) {
            const float4 fv = *(const float4*)(fr + q * 4);
            const float fa[4] = {fv.x, fv.y, fv.z, fv.w};
            #pragma unroll
            for (int t = 0; t < 4; ++t) {
                const float4 w = *(const float4*)&Ws[(q * 4 + t) * HD + lane * 4];
                ax += fa[t] * w.x; ay += fa[t] * w.y;
                az += fa[t] * w.z; aw += fa[t] * w.w;
            }
        }
        const size_t base = (size_t)row * HD + lane * 4;
        ushort4 bi;
        bi.x = f2b(ax); bi.y = f2b(ay); bi.z = f2b(az); bi.w = f2b(aw);
        *(ushort4*)(g_binH + base) = bi;
        ushort4 o;
        o.x = f2b(fmaxf(ax, 0.f)); o.y = f2b(fmaxf(ay, 0.f));
        o.z = f2b(fmaxf(az, 0.f)); o.w = f2b(fmaxf(aw, 0.f));
        *(ushort4*)(g_msg0 + base) = o;
    }
}

// ------- K2: MFMA GEMM — dst[row] = bf16(pool[row] @ W) with split-bf16 W -------
// sel 0: src msg0, W=Wh,  dst P   | sel 1: src msg1, W=Wh, dst P
// sel 2: src msg0, W=Wo_mid, dst Q
// One wave = 16 pool rows x 256 cols. No LDS, no barriers in K-loop.
// b_frag: lane holds pool[base+(lane&15)][k0+(lane>>4)*8 .. +7] (one 16B load).
// a_frag: packed weights (16B load). D: col n = t*16+(lane>>4)*4+reg, row = lane&15.
__global__ __launch_bounds__(256, 4)
void k_gemmMF(int sel, int rowStart, int rowEnd)
{
    const u16* msrc = (sel == 1) ? g_msg1 : g_msg0;
    const u16* pHi  = (sel == 2) ? g_pWo_hi : g_pWh_hi;
    const u16* pLo  = (sel == 2) ? g_pWo_lo : g_pWh_lo;
    u16* dst        = (sel == 2) ? g_Q : g_P;

    const int tid  = threadIdx.x;
    const int lane = tid & 63;
    const int wv   = tid >> 6;
    const int l15  = lane & 15;
    const int quad = lane >> 4;
    const int rowIdeal = rowStart + blockIdx.x * 64 + wv * 16 + l15;
    const int row = (rowIdeal < rowEnd) ? rowIdeal : (rowEnd - 1);
    const u16* srow = (row < M_N) ? (g_tmsgh + (size_t)row * HD)
                                  : (msrc + (size_t)(row - M_N) * HD);

    f32x4 acc[16];
    #pragma unroll
    for (int t = 0; t < 16; ++t) acc[t] = (f32x4){0.f, 0.f, 0.f, 0.f};

    #pragma unroll 1
    for (int c = 0; c < 8; ++c) {
        const bf16x8 b = *(const bf16x8*)(srow + c * 32 + quad * 8);
        const u16* ph = pHi + ((size_t)(c * 16) * 64 + lane) * 8;
        const u16* pl = pLo + ((size_t)(c * 16) * 64 + lane) * 8;
        #pragma unroll 4
        for (int t = 0; t < 16; ++t) {
            const bf16x8 ah = *(const bf16x8*)(ph + (size_t)t * 512);
            acc[t] = __builtin_amdgcn_mfma_f32_16x16x32_bf16(ah, b, acc[t], 0, 0, 0);
            const bf16x8 al = *(const bf16x8*)(pl + (size_t)t * 512);
            acc[t] = __builtin_amdgcn_mfma_f32_16x16x32_bf16(al, b, acc[t], 0, 0, 0);
        }
    }

    if (rowIdeal < rowEnd) {
        u16* drow = dst + (size_t)rowIdeal * HD + quad * 4;
        #pragma unroll
        for (int t = 0; t < 16; ++t) {
            ushort4 o;
            o.x = f2b(acc[t][0]); o.y = f2b(acc[t][1]);
            o.z = f2b(acc[t][2]); o.w = f2b(acc[t][3]);
            *(ushort4*)(drow + t * 16) = o;
        }
    }
}

// ------- K3: dst = bf16(relu(binH + sum_j P[bgraph[r][j]])) — pure gather -------
__global__ __launch_bounds__(256)
void k_gather(const int* __restrict__ bgraph, int dstSel)
{
    u16* dst = dstSel ? g_msg1 : g_msg0;
    __shared__ int idx_s[8][MAX_NB];
    const int tid = threadIdx.x;
    const int rowBase = blockIdx.x * 8;
    if (tid < 8 * MAX_NB) {
        const int r = tid / MAX_NB;
        const int j = tid - r * MAX_NB;
        idx_s[r][j] = bgraph[(size_t)(rowBase + r) * MAX_NB + j];
    }
    __syncthreads();
    const int rl = tid >> 5;           // [0,8)
    const int c  = (tid & 31) << 3;    // 8 bf16 = 16 B per thread
    const int row = rowBase + rl;

    float s[8] = {0.f,0.f,0.f,0.f,0.f,0.f,0.f,0.f};
    #pragma unroll
    for (int j = 0; j < MAX_NB; ++j) {
        const uint4 v = *(const uint4*)(g_P + (size_t)idx_s[rl][j] * HD + c);
        s[0] += blo(v.x); s[1] += bhi(v.x);
        s[2] += blo(v.y); s[3] += bhi(v.y);
        s[4] += blo(v.z); s[5] += bhi(v.z);
        s[6] += blo(v.w); s[7] += bhi(v.w);
    }
    const uint4 bv = *(const uint4*)(g_binH + (size_t)row * HD + c);
    uint4 w;
    w.x = ((unsigned)f2b(fmaxf(s[0] + blo(bv.x), 0.f)))
        | ((unsigned)f2b(fmaxf(s[1] + bhi(bv.x), 0.f)) << 16);
    w.y = ((unsigned)f2b(fmaxf(s[2] + blo(bv.y), 0.f)))
        | ((unsigned)f2b(fmaxf(s[3] + bhi(bv.y), 0.f)) << 16);
    w.z = ((unsigned)f2b(fmaxf(s[4] + blo(bv.z), 0.f)))
        | ((unsigned)f2b(fmaxf(s[5] + bhi(bv.z), 0.f)) << 16);
    w.w = ((unsigned)f2b(fmaxf(s[6] + blo(bv.w), 0.f)))
        | ((unsigned)f2b(fmaxf(s[7] + bhi(bv.w), 0.f)) << 16);
    *(uint4*)(dst + (size_t)row * HD + c) = w;
}

// ------- K4: F = fatoms @ Wo[0:35] + bias (fp32) -------
__global__ __launch_bounds__(256)
void k_F(const float* __restrict__ fatoms, const float* __restrict__ Wo,
         const float* __restrict__ bias)
{
    __shared__ float Ws[ATOM_FDIM * HD];   // 35 KB
    __shared__ float bs[HD];
    for (int i = threadIdx.x; i < ATOM_FDIM * HD; i += 256) Ws[i] = Wo[i];
    for (int i = threadIdx.x; i < HD; i += 256) bs[i] = bias[i];
    __syncthreads();
    const int lane = threadIdx.x & 63;
    const int wid  = (blockIdx.x * 256 + threadIdx.x) >> 6;
    const int nw   = (gridDim.x * 256) >> 6;
    for (int row = wid; row < A_N; row += nw) {
        const float* fr = fatoms + (size_t)row * ATOM_FDIM;
        const float4 b4 = *(const float4*)&bs[lane * 4];
        float ax = b4.x, ay = b4.y, az = b4.z, aw = b4.w;
        #pragma unroll 5
        for (int k = 0; k < ATOM_FDIM; ++k) {
            const float f = fr[k];
            const float4 w = *(const float4*)&Ws[k * HD + lane * 4];
            ax += f * w.x; ay += f * w.y; az += f * w.z; aw += f * w.w;
        }
        float4 o; o.x = ax; o.y = ay; o.z = az; o.w = aw;
        *(float4*)(g_F + (size_t)row * HD + lane * 4) = o;
    }
}

// ------- K5: out[mol] += relu(F[a] + sum_j Q[agraph[a][j]]) — gather + segsum -------
__global__ __launch_bounds__(256)
void k_gatherA(const int* __restrict__ agraph, const int* __restrict__ scope,
               float* __restrict__ out)
{
    __shared__ int idx_s[64 * MAX_NB];
    __shared__ int sc_s[64];
    const int tid = threadIdx.x;
    const int rb = blockIdx.x * 64;
    for (int i = tid; i < 64 * MAX_NB; i += 256) {
        const int a = rb + i / MAX_NB;
        idx_s[i] = (a < A_N) ? agraph[(size_t)a * MAX_NB + (i % MAX_NB)] : 0;
    }
    if (tid < 64) sc_s[tid] = (rb + tid < A_N) ? scope[rb + tid] : -1;
    __syncthreads();

    const int grp = tid >> 5;          // 8 atoms per group, processed sequentially
    const int c = (tid & 31) * 8;      // 8 cols per thread
    float s[8] = {0.f,0.f,0.f,0.f,0.f,0.f,0.f,0.f};
    int prev = -1;
    #pragma unroll 1
    for (int i = 0; i < 8; ++i) {
        const int al = grp * 8 + i;
        const int a = rb + al;
        if (a < A_N) {
            const int m = sc_s[al];
            if (m != prev) {
                if (prev >= 0) {
                    float* dst = out + (size_t)prev * HD + c;
                    #pragma unroll
                    for (int q = 0; q < 8; ++q) atomicAdd(dst + q, s[q]);
                    #pragma unroll
                    for (int q = 0; q < 8; ++q) s[q] = 0.f;
                }
                prev = m;
            }
            float g0=0.f,g1=0.f,g2=0.f,g3=0.f,g4=0.f,g5=0.f,g6=0.f,g7=0.f;
            #pragma unroll
            for (int j = 0; j < MAX_NB; ++j) {
                const uint4 v = *(const uint4*)(g_Q + (size_t)idx_s[al * MAX_NB + j] * HD + c);
                g0 += blo(v.x); g1 += bhi(v.x);
                g2 += blo(v.y); g3 += bhi(v.y);
                g4 += blo(v.z); g5 += bhi(v.z);
                g6 += blo(v.w); g7 += bhi(v.w);
            }
            const float4 f0 = *(const float4*)(g_F + (size_t)a * HD + c);
            const float4 f1 = *(const float4*)(g_F + (size_t)a * HD + c + 4);
            s[0] += fmaxf(g0 + f0.x, 0.f); s[1] += fmaxf(g1 + f0.y, 0.f);
            s[2] += fmaxf(g2 + f0.z, 0.f); s[3] += fmaxf(g3 + f0.w, 0.f);
            s[4] += fmaxf(g4 + f1.x, 0.f); s[5] += fmaxf(g5 + f1.y, 0.f);
            s[6] += fmaxf(g6 + f1.z, 0.f); s[7] += fmaxf(g7 + f1.w, 0.f);
        }
    }
    if (prev >= 0) {
        float* dst = out + (size_t)prev * HD + c;
        #pragma unroll
        for (int q = 0; q < 8; ++q) atomicAdd(dst + q, s[q]);
    }
}

// ---------------- counts + divide ----------------
__global__ __launch_bounds__(256)
void k_counts(const int* __restrict__ scope)
{
    const int a = blockIdx.x * 256 + threadIdx.x;
    if (a < A_N) atomicAdd(&g_counts[scope[a]], 1.0f);
}

__global__ __launch_bounds__(256)
void k_div(float* __restrict__ out)
{
    const int idx = blockIdx.x * 256 + threadIdx.x;
    out[idx] = out[idx] / fmaxf(g_counts[idx >> 8], 1.0f);
}

// ---------------- launch ----------------
extern "C" void kernel_launch(void* const* d_in, const int* in_sizes, int n_in,
                              void* d_out, int out_size, void* d_ws, size_t ws_size,
                              hipStream_t stream)
{
    const float* fatoms = (const float*)d_in[0];
    const float* fbonds = (const float*)d_in[1];
    const int*   agraph = (const int*)d_in[2];
    const int*   bgraph = (const int*)d_in[3];
    const float* tmsg   = (const float*)d_in[4];
    const int*   scope  = (const int*)d_in[5];
    const float* W_i    = (const float*)d_in[6];
    const float* W_h    = (const float*)d_in[7];
    const float* W_o    = (const float*)d_in[8];
    const float* W_ob   = (const float*)d_in[9];
    float* out = (float*)d_out;

    (void)d_ws; (void)ws_size;

    k_zero_out<<<(N_MOLS * HD + 255) / 256, 256, 0, stream>>>(out, N_MOLS * HD);
    k_zero_counts<<<(N_MOLS + 255) / 256, 256, 0, stream>>>();
    k_cvt<<<(M_N * HD / 4 + 255) / 256, 256, 0, stream>>>(tmsg);
    k_packW<<<32, 256, 0, stream>>>(W_h, W_o);

    k_in<<<4096, 256, 0, stream>>>(fbonds, W_i);            // binH + msg0

    // iter 0: P = [tmsg; msg0] @ Wh; msg1 = relu(binH + gatherP)
    k_gemmMF<<<(POOL_N + 63) / 64, 256, 0, stream>>>(0, 0, POOL_N);
    k_gather<<<B_N / 8, 256, 0, stream>>>(bgraph, 1);
    // iter 1: only msg rows of P change
    k_gemmMF<<<(B_N + 63) / 64, 256, 0, stream>>>(1, M_N, POOL_N);
    k_gather<<<B_N / 8, 256, 0, stream>>>(bgraph, 0);

    // readout: Q = [tmsg; msg0] @ Wo[35:291]; F = fatoms@Wo[0:35]+b; gather+segsum
    k_gemmMF<<<(POOL_N + 63) / 64, 256, 0, stream>>>(2, 0, POOL_N);
    k_F<<<2048, 256, 0, stream>>>(fatoms, W_o, W_ob);
    k_counts<<<(A_N + 255) / 256, 256, 0, stream>>>(scope);
    k_gatherA<<<(A_N + 63) / 64, 256, 0, stream>>>(agraph, scope, out);
    k_div<<<(N_MOLS * HD) / 256, 256, 0, stream>>>(out);
}

// Round 11
// 1483.368 us; speedup vs baseline: 2.2926x; 2.2926x over previous
//
#include <hip/hip_runtime.h>
#include <cstdint>
#include <cstddef>

#define A_N 100000
#define B_N 200000
#define M_N 20000
#define POOL_N 220000   // M_N + B_N
#define HD 256
#define MAX_NB 10
#define N_MOLS 2000
#define ATOM_FDIM 35
#define FB_DIM 40

typedef unsigned short u16;
typedef __attribute__((ext_vector_type(8))) short bf16x8;
typedef __attribute__((ext_vector_type(4))) float f32x4;

// Static device buffers (BSS, ~646 MB).
__device__ u16 g_msg0[(size_t)B_N * HD];      // bf16 messages (ping)
__device__ u16 g_msg1[(size_t)B_N * HD];      // bf16 messages (pong)
__device__ u16 g_tmsgh[(size_t)M_N * HD];     // bf16 tree messages
__device__ u16 g_P[(size_t)POOL_N * HD];      // P = pool @ W_h   (bf16)
__device__ u16 g_Q[(size_t)POOL_N * HD];      // Q = pool @ Wo[35:291] (bf16)
__device__ u16 g_binH[(size_t)B_N * HD];      // bf16 binput
__device__ float g_F[(size_t)A_N * HD];       // fp32 fatoms@Wo_top + bias
// packed split-bf16 weights in MFMA A-fragment order: [(c*16+t)*64+lane]*8+j
__device__ u16 g_pWh_hi[65536], g_pWh_lo[65536];
__device__ u16 g_pWo_hi[65536], g_pWo_lo[65536];
__device__ float g_counts[N_MOLS];

__device__ __forceinline__ u16 f2b(float f)
{
    union { float f; unsigned u; } x; x.f = f;
    const unsigned r = x.u + 0x7FFFu + ((x.u >> 16) & 1u);
    return (u16)(r >> 16);
}
__device__ __forceinline__ float b2f(u16 h) { return __uint_as_float((unsigned)h << 16); }
__device__ __forceinline__ float blo(unsigned u) { return __uint_as_float(u << 16); }
__device__ __forceinline__ float bhi(unsigned u) { return __uint_as_float(u & 0xffff0000u); }

// ---------------- setup kernels ----------------
__global__ __launch_bounds__(256)
void k_zero_out(float* __restrict__ p, int n)
{
    const int i = blockIdx.x * 256 + threadIdx.x;
    if (i < n) p[i] = 0.f;
}

__global__ __launch_bounds__(256)
void k_zero_counts()
{
    const int i = blockIdx.x * 256 + threadIdx.x;
    if (i < N_MOLS) g_counts[i] = 0.f;
}

__global__ __launch_bounds__(256)
void k_cvt(const float* __restrict__ tmsg)
{
    const int i = (blockIdx.x * 256 + threadIdx.x) * 4;
    if (i < M_N * HD) {
        const float4 v = *(const float4*)(tmsg + i);
        ushort4 o;
        o.x = f2b(v.x); o.y = f2b(v.y); o.z = f2b(v.z); o.w = f2b(v.w);
        *(ushort4*)(g_tmsgh + i) = o;
    }
}

// pack Wh and Wo[35:291] into split-bf16 MFMA A-fragment layout.
//   packed[((c*16+t)*64+lane)*8+j] = W[c*32+(lane>>4)*8+j][t*16+(lane&15)]
__global__ __launch_bounds__(256)
void k_packW(const float* __restrict__ Wh, const float* __restrict__ Wo)
{
    const int id = blockIdx.x * 256 + threadIdx.x;   // 0..8191
    if (id >= 8192) return;
    const int l = id & 63;
    const int t = (id >> 6) & 15;
    const int c = id >> 10;
    const int n = t * 16 + (l & 15);
    const int kb = c * 32 + ((l >> 4) << 3);
    const size_t base = (size_t)id * 8;
    #pragma unroll
    for (int j = 0; j < 8; ++j) {
        const int k = kb + j;
        const float wh = Wh[(size_t)k * HD + n];
        const u16 hh = f2b(wh);
        g_pWh_hi[base + j] = hh;
        g_pWh_lo[base + j] = f2b(wh - b2f(hh));
        const float wo = Wo[(size_t)(35 + k) * HD + n];
        const u16 oh = f2b(wo);
        g_pWo_hi[base + j] = oh;
        g_pWo_lo[base + j] = f2b(wo - b2f(oh));
    }
}

// ---------------- K1: binH = bf16(fbonds @ W_i); msg0 = bf16(relu(binput)) ----------------
__global__ __launch_bounds__(256)
void k_in(const float* __restrict__ fbonds, const float* __restrict__ Wi)
{
    __shared__ float Ws[FB_DIM * HD];                      // 40 KB
    for (int i = threadIdx.x; i < FB_DIM * HD; i += 256) Ws[i] = Wi[i];
    __syncthreads();
    const int lane = threadIdx.x & 63;
    const int wid  = (blockIdx.x * 256 + threadIdx.x) >> 6;
    const int nw   = (gridDim.x * 256) >> 6;
    for (int row = wid; row < B_N; row += nw) {
        const float* fr = fbonds + (size_t)row * FB_DIM;
        float ax = 0.f, ay = 0.f, az = 0.f, aw = 0.f;
        #pragma unroll
        for (int q = 0; q < FB_DIM / 4; ++q) {
            const float4 fv = *(const float4*)(fr + q * 4);
            const float fa[4] = {fv.x, fv.y, fv.z, fv.w};
            #pragma unroll
            for (int t = 0; t < 4; ++t) {
                const float4 w = *(const float4*)&Ws[(q * 4 + t) * HD + lane * 4];
                ax += fa[t] * w.x; ay += fa[t] * w.y;
                az += fa[t] * w.z; aw += fa[t] * w.w;
            }
        }
        const size_t base = (size_t)row * HD + lane * 4;
        ushort4 bi;
        bi.x = f2b(ax); bi.y = f2b(ay); bi.z = f2b(az); bi.w = f2b(aw);
        *(ushort4*)(g_binH + base) = bi;
        ushort4 o;
        o.x = f2b(fmaxf(ax, 0.f)); o.y = f2b(fmaxf(ay, 0.f));
        o.z = f2b(fmaxf(az, 0.f)); o.w = f2b(fmaxf(aw, 0.f));
        *(ushort4*)(g_msg0 + base) = o;
    }
}

// ------- K2: MFMA GEMM — dst[row] = bf16(pool[row] @ W) with split-bf16 W -------
// R10 post-mortem: `#pragma unroll 4` on the 16-tile loop left a runtime loop
// base -> acc[] dynamically indexed -> scratch (2.07 GB writes, MfmaUtil 2.7%).
// Fix: wave tile = 16 rows x 128 cols (acc[8]=32 regs), t-loop FULLY unrolled
// (static acc). Block = 4 waves = 32 rows x 256 cols. No LDS, no K-loop barriers.
// Layouts identical to R10 (validated): A=packed W frag, B=msg rows frag,
// D: msg-row = lane&15, col-in-tile = quad*4+reg.
__global__ __launch_bounds__(256, 4)
void k_gemmMF(int sel, int rowStart, int rowEnd)
{
    const u16* msrc = (sel == 1) ? g_msg1 : g_msg0;
    const u16* pHi  = (sel == 2) ? g_pWo_hi : g_pWh_hi;
    const u16* pLo  = (sel == 2) ? g_pWo_lo : g_pWh_lo;
    u16* dst        = (sel == 2) ? g_Q : g_P;

    const int tid  = threadIdx.x;
    const int lane = tid & 63;
    const int wv   = tid >> 6;            // 0..3
    const int l15  = lane & 15;
    const int quad = lane >> 4;
    const int tOff = (wv & 1) * 8;        // col-half: tiles [tOff, tOff+8)
    const int rowIdeal = rowStart + blockIdx.x * 32 + (wv >> 1) * 16 + l15;
    const int row = (rowIdeal < rowEnd) ? rowIdeal : (rowEnd - 1);
    const u16* srow = (row < M_N) ? (g_tmsgh + (size_t)row * HD)
                                  : (msrc + (size_t)(row - M_N) * HD);

    f32x4 acc[8];
    #pragma unroll
    for (int t = 0; t < 8; ++t) acc[t] = (f32x4){0.f, 0.f, 0.f, 0.f};

    #pragma unroll 1
    for (int c = 0; c < 8; ++c) {
        const bf16x8 b = *(const bf16x8*)(srow + c * 32 + quad * 8);
        const u16* ph = pHi + ((size_t)(c * 16 + tOff) * 64 + lane) * 8;
        const u16* pl = pLo + ((size_t)(c * 16 + tOff) * 64 + lane) * 8;
        #pragma unroll
        for (int t = 0; t < 8; ++t) {
            const bf16x8 ah = *(const bf16x8*)(ph + (size_t)t * 512);
            acc[t] = __builtin_amdgcn_mfma_f32_16x16x32_bf16(ah, b, acc[t], 0, 0, 0);
        }
        #pragma unroll
        for (int t = 0; t < 8; ++t) {
            const bf16x8 al = *(const bf16x8*)(pl + (size_t)t * 512);
            acc[t] = __builtin_amdgcn_mfma_f32_16x16x32_bf16(al, b, acc[t], 0, 0, 0);
        }
    }

    if (rowIdeal < rowEnd) {
        u16* drow = dst + (size_t)rowIdeal * HD + tOff * 16 + quad * 4;
        #pragma unroll
        for (int t = 0; t < 8; ++t) {
            ushort4 o;
            o.x = f2b(acc[t][0]); o.y = f2b(acc[t][1]);
            o.z = f2b(acc[t][2]); o.w = f2b(acc[t][3]);
            *(ushort4*)(drow + t * 16) = o;
        }
    }
}

// ------- K3: dst = bf16(relu(binH + sum_j P[bgraph[r][j]])) — pure gather -------
__global__ __launch_bounds__(256)
void k_gather(const int* __restrict__ bgraph, int dstSel)
{
    u16* dst = dstSel ? g_msg1 : g_msg0;
    __shared__ int idx_s[8][MAX_NB];
    const int tid = threadIdx.x;
    const int rowBase = blockIdx.x * 8;
    if (tid < 8 * MAX_NB) {
        const int r = tid / MAX_NB;
        const int j = tid - r * MAX_NB;
        idx_s[r][j] = bgraph[(size_t)(rowBase + r) * MAX_NB + j];
    }
    __syncthreads();
    const int rl = tid >> 5;           // [0,8)
    const int c  = (tid & 31) << 3;    // 8 bf16 = 16 B per thread
    const int row = rowBase + rl;

    float s[8] = {0.f,0.f,0.f,0.f,0.f,0.f,0.f,0.f};
    #pragma unroll
    for (int j = 0; j < MAX_NB; ++j) {
        const uint4 v = *(const uint4*)(g_P + (size_t)idx_s[rl][j] * HD + c);
        s[0] += blo(v.x); s[1] += bhi(v.x);
        s[2] += blo(v.y); s[3] += bhi(v.y);
        s[4] += blo(v.z); s[5] += bhi(v.z);
        s[6] += blo(v.w); s[7] += bhi(v.w);
    }
    const uint4 bv = *(const uint4*)(g_binH + (size_t)row * HD + c);
    uint4 w;
    w.x = ((unsigned)f2b(fmaxf(s[0] + blo(bv.x), 0.f)))
        | ((unsigned)f2b(fmaxf(s[1] + bhi(bv.x), 0.f)) << 16);
    w.y = ((unsigned)f2b(fmaxf(s[2] + blo(bv.y), 0.f)))
        | ((unsigned)f2b(fmaxf(s[3] + bhi(bv.y), 0.f)) << 16);
    w.z = ((unsigned)f2b(fmaxf(s[4] + blo(bv.z), 0.f)))
        | ((unsigned)f2b(fmaxf(s[5] + bhi(bv.z), 0.f)) << 16);
    w.w = ((unsigned)f2b(fmaxf(s[6] + blo(bv.w), 0.f)))
        | ((unsigned)f2b(fmaxf(s[7] + bhi(bv.w), 0.f)) << 16);
    *(uint4*)(dst + (size_t)row * HD + c) = w;
}

// ------- K4: F = fatoms @ Wo[0:35] + bias (fp32) -------
__global__ __launch_bounds__(256)
void k_F(const float* __restrict__ fatoms, const float* __restrict__ Wo,
         const float* __restrict__ bias)
{
    __shared__ float Ws[ATOM_FDIM * HD];   // 35 KB
    __shared__ float bs[HD];
    for (int i = threadIdx.x; i < ATOM_FDIM * HD; i += 256) Ws[i] = Wo[i];
    for (int i = threadIdx.x; i < HD; i += 256) bs[i] = bias[i];
    __syncthreads();
    const int lane = threadIdx.x & 63;
    const int wid  = (blockIdx.x * 256 + threadIdx.x) >> 6;
    const int nw   = (gridDim.x * 256) >> 6;
    for (int row = wid; row < A_N; row += nw) {
        const float* fr = fatoms + (size_t)row * ATOM_FDIM;
        const float4 b4 = *(const float4*)&bs[lane * 4];
        float ax = b4.x, ay = b4.y, az = b4.z, aw = b4.w;
        #pragma unroll 5
        for (int k = 0; k < ATOM_FDIM; ++k) {
            const float f = fr[k];
            const float4 w = *(const float4*)&Ws[k * HD + lane * 4];
            ax += f * w.x; ay += f * w.y; az += f * w.z; aw += f * w.w;
        }
        float4 o; o.x = ax; o.y = ay; o.z = az; o.w = aw;
        *(float4*)(g_F + (size_t)row * HD + lane * 4) = o;
    }
}

// ------- K5: out[mol] += relu(F[a] + sum_j Q[agraph[a][j]]) — gather + segsum -------
__global__ __launch_bounds__(256)
void k_gatherA(const int* __restrict__ agraph, const int* __restrict__ scope,
               float* __restrict__ out)
{
    __shared__ int idx_s[64 * MAX_NB];
    __shared__ int sc_s[64];
    const int tid = threadIdx.x;
    const int rb = blockIdx.x * 64;
    for (int i = tid; i < 64 * MAX_NB; i += 256) {
        const int a = rb + i / MAX_NB;
        idx_s[i] = (a < A_N) ? agraph[(size_t)a * MAX_NB + (i % MAX_NB)] : 0;
    }
    if (tid < 64) sc_s[tid] = (rb + tid < A_N) ? scope[rb + tid] : -1;
    __syncthreads();

    const int grp = tid >> 5;          // 8 atoms per group, processed sequentially
    const int c = (tid & 31) * 8;      // 8 cols per thread
    float s[8] = {0.f,0.f,0.f,0.f,0.f,0.f,0.f,0.f};
    int prev = -1;
    #pragma unroll 1
    for (int i = 0; i < 8; ++i) {
        const int al = grp * 8 + i;
        const int a = rb + al;
        if (a < A_N) {
            const int m = sc_s[al];
            if (m != prev) {
                if (prev >= 0) {
                    float* dst = out + (size_t)prev * HD + c;
                    #pragma unroll
                    for (int q = 0; q < 8; ++q) atomicAdd(dst + q, s[q]);
                    #pragma unroll
                    for (int q = 0; q < 8; ++q) s[q] = 0.f;
                }
                prev = m;
            }
            float g0=0.f,g1=0.f,g2=0.f,g3=0.f,g4=0.f,g5=0.f,g6=0.f,g7=0.f;
            #pragma unroll
            for (int j = 0; j < MAX_NB; ++j) {
                const uint4 v = *(const uint4*)(g_Q + (size_t)idx_s[al * MAX_NB + j] * HD + c);
                g0 += blo(v.x); g1 += bhi(v.x);
                g2 += blo(v.y); g3 += bhi(v.y);
                g4 += blo(v.z); g5 += bhi(v.z);
                g6 += blo(v.w); g7 += bhi(v.w);
            }
            const float4 f0 = *(const float4*)(g_F + (size_t)a * HD + c);
            const float4 f1 = *(const float4*)(g_F + (size_t)a * HD + c + 4);
            s[0] += fmaxf(g0 + f0.x, 0.f); s[1] += fmaxf(g1 + f0.y, 0.f);
            s[2] += fmaxf(g2 + f0.z, 0.f); s[3] += fmaxf(g3 + f0.w, 0.f);
            s[4] += fmaxf(g4 + f1.x, 0.f); s[5] += fmaxf(g5 + f1.y, 0.f);
            s[6] += fmaxf(g6 + f1.z, 0.f); s[7] += fmaxf(g7 + f1.w, 0.f);
        }
    }
    if (prev >= 0) {
        float* dst = out + (size_t)prev * HD + c;
        #pragma unroll
        for (int q = 0; q < 8; ++q) atomicAdd(dst + q, s[q]);
    }
}

// ---------------- counts + divide ----------------
__global__ __launch_bounds__(256)
void k_counts(const int* __restrict__ scope)
{
    const int a = blockIdx.x * 256 + threadIdx.x;
    if (a < A_N) atomicAdd(&g_counts[scope[a]], 1.0f);
}

__global__ __launch_bounds__(256)
void k_div(float* __restrict__ out)
{
    const int idx = blockIdx.x * 256 + threadIdx.x;
    out[idx] = out[idx] / fmaxf(g_counts[idx >> 8], 1.0f);
}

// ---------------- launch ----------------
extern "C" void kernel_launch(void* const* d_in, const int* in_sizes, int n_in,
                              void* d_out, int out_size, void* d_ws, size_t ws_size,
                              hipStream_t stream)
{
    const float* fatoms = (const float*)d_in[0];
    const float* fbonds = (const float*)d_in[1];
    const int*   agraph = (const int*)d_in[2];
    const int*   bgraph = (const int*)d_in[3];
    const float* tmsg   = (const float*)d_in[4];
    const int*   scope  = (const int*)d_in[5];
    const float* W_i    = (const float*)d_in[6];
    const float* W_h    = (const float*)d_in[7];
    const float* W_o    = (const float*)d_in[8];
    const float* W_ob   = (const float*)d_in[9];
    float* out = (float*)d_out;

    (void)d_ws; (void)ws_size;

    k_zero_out<<<(N_MOLS * HD + 255) / 256, 256, 0, stream>>>(out, N_MOLS * HD);
    k_zero_counts<<<(N_MOLS + 255) / 256, 256, 0, stream>>>();
    k_cvt<<<(M_N * HD / 4 + 255) / 256, 256, 0, stream>>>(tmsg);
    k_packW<<<32, 256, 0, stream>>>(W_h, W_o);

    k_in<<<4096, 256, 0, stream>>>(fbonds, W_i);            // binH + msg0

    // iter 0: P = [tmsg; msg0] @ Wh; msg1 = relu(binH + gatherP)
    k_gemmMF<<<(POOL_N + 31) / 32, 256, 0, stream>>>(0, 0, POOL_N);
    k_gather<<<B_N / 8, 256, 0, stream>>>(bgraph, 1);
    // iter 1: only msg rows of P change
    k_gemmMF<<<(B_N + 31) / 32, 256, 0, stream>>>(1, M_N, POOL_N);
    k_gather<<<B_N / 8, 256, 0, stream>>>(bgraph, 0);

    // readout: Q = [tmsg; msg0] @ Wo[35:291]; F = fatoms@Wo[0:35]+b; gather+segsum
    k_gemmMF<<<(POOL_N + 31) / 32, 256, 0, stream>>>(2, 0, POOL_N);
    k_F<<<2048, 256, 0, stream>>>(fatoms, W_o, W_ob);
    k_counts<<<(A_N + 255) / 256, 256, 0, stream>>>(scope);
    k_gatherA<<<(A_N + 63) / 64, 256, 0, stream>>>(agraph, scope, out);
    k_div<<<(N_MOLS * HD) / 256, 256, 0, stream>>>(out);
}